// Round 17
// baseline (150.238 us; speedup 1.0000x reference)
//
#include <hip/hip_runtime.h>
#include <hip/hip_bf16.h>

#define B_ 8
#define H_ 56
#define W_ 56
#define C_ 384
#define HEADS_ 12
#define NPIX (B_*H_*W_)      // 25088
#define NPAD 1408            // 1356 padded to 11*128
#define KDIM 384

typedef unsigned short u16;
typedef __attribute__((ext_vector_type(4))) float f32x4;
typedef __attribute__((ext_vector_type(8))) short bf16x8;
typedef __attribute__((ext_vector_type(8))) unsigned short u16x8;

#define GLDS16(g, l)                                                            \
    __builtin_amdgcn_global_load_lds(                                           \
        (const __attribute__((address_space(1))) void*)(g),                     \
        (__attribute__((address_space(3))) void*)(l), 16, 0, 0)

__device__ __forceinline__ float bf2f(u16 u) {
    union { unsigned int uu; float f; } cv; cv.uu = ((unsigned)u) << 16; return cv.f;
}
__device__ __forceinline__ u16 f2bf(float f) {
    __hip_bfloat16 hb = __float2bfloat16(f);
    return *reinterpret_cast<u16*>(&hb);
}

// packed-pair LDS offset (u16 units) within one 128x32 tile (8KB), R4-verified
// zero-conflict: two 32-k rows share a 128B line; 8x16B slots XOR'd by line idx.
__device__ __forceinline__ int foff(int row, int kg) {
    int lrow = row >> 1;
    int s = (((row & 1) << 2) | kg) ^ (lrow & 7);
    return (lrow << 6) + (s << 3);
}

// ---------------- pack: fp32 -> bf16 (x vectorized, [Wv;Wa;0], Wo) ----------------
__global__ void pack_kernel(const float* __restrict__ x, const float* __restrict__ Wv,
                            const float* __restrict__ Wa, const float* __restrict__ Wo,
                            u16* __restrict__ xb, __hip_bfloat16* __restrict__ wcat,
                            __hip_bfloat16* __restrict__ wob) {
    const int NX8 = NPIX * C_ / 8;   // 1204224 (x in 8-float chunks)
    const int NW = NPAD * KDIM;      // 540672
    const int NO = C_ * C_;          // 147456
    const int total = NX8 + NW + NO;
    for (int idx = blockIdx.x * blockDim.x + threadIdx.x; idx < total;
         idx += gridDim.x * blockDim.x) {
        if (idx < NX8) {
            float4 a = ((const float4*)x)[idx * 2];
            float4 b = ((const float4*)x)[idx * 2 + 1];
            u16x8 o;
            o[0] = f2bf(a.x); o[1] = f2bf(a.y); o[2] = f2bf(a.z); o[3] = f2bf(a.w);
            o[4] = f2bf(b.x); o[5] = f2bf(b.y); o[6] = f2bf(b.z); o[7] = f2bf(b.w);
            ((u16x8*)xb)[idx] = o;
        } else if (idx < NX8 + NW) {
            int t = idx - NX8;
            int o = t / KDIM;
            float v = 0.f;
            if (o < 384) v = Wv[t];
            else if (o < 1356) v = Wa[t - 147456];
            wcat[t] = __float2bfloat16(v);
        } else {
            int t = idx - NX8 - NW;
            wob[t] = __float2bfloat16(Wo[t]);
        }
    }
}

// ---------------- bf16 MFMA GEMM: C[M,N] = A[M,K] * B[N,K]^T ----------------
// R15 base (BK=32 double-buffered A, packed-pair zero-conflict LDS, prefetch,
// XCD chunk swizzle) with ONE change: B skips LDS entirely — each wave loads
// its 4 B-fragments per K-step directly global->VGPR (B is L2-resident: wcat
// 1.08MB / wob 288KB). Halves the bytes drained per barrier, LDS 32->16KB.
#define STAGE_A(buf_, kt_) do {                                                      \
    _Pragma("unroll") for (int j = 0; j < 2; ++j) {                                  \
        int chunk = wid * 128 + j * 64 + lane;      /* 0..511 16B chunks */          \
        int lrow = chunk >> 3, sl = chunk & 7;                                       \
        int u = sl ^ (lrow & 7);                                                     \
        int grow = lrow * 2 + (u >> 2);                                              \
        int gcol = (u & 3) << 3;                                                     \
        GLDS16(&A[(size_t)(bm * 128 + grow) * K + (kt_) + gcol],                     \
               &As[buf_][(wid * 128 + j * 64) * 8]);                                 \
    } } while (0)

template<int OUT_BF16>
__global__ __launch_bounds__(256) void gemm_bt(const u16* __restrict__ A, const u16* __restrict__ Bw,
                                               void* __restrict__ Cout, int N, int K,
                                               int gridN, int q, int r) {
    __shared__ u16 As[2][128 * 32];
    const int bid = blockIdx.x;
    const int xcd = bid & 7, ii = bid >> 3;
    const int logical = (xcd < r) ? xcd * (q + 1) + ii : r * (q + 1) + (xcd - r) * q + ii;
    const int bm = logical / gridN, bn = logical - bm * gridN;
    const int tid = threadIdx.x;
    const int lane = tid & 63, wid = tid >> 6;
    const int wm = wid >> 1, wn = wid & 1;
    const int fr = lane & 15;    // fragment row/col within 16
    const int kg = lane >> 4;    // k-group 0..3 (8 contiguous k each)
    const int NT = K >> 5;       // 12 for K=384
    f32x4 acc[4][4] = {};

    int offA[4];
    const u16* bp[4];
#pragma unroll
    for (int m = 0; m < 4; ++m) {
        offA[m] = foff(wm * 64 + m * 16 + fr, kg);
        bp[m] = Bw + (size_t)(bn * 128 + wn * 64 + m * 16 + fr) * K + kg * 8;
    }

    STAGE_A(0, 0);
    __syncthreads();
    for (int t = 0; t < NT; ++t) {
        const int cur = t & 1;
        if (t + 1 < NT) STAGE_A((t + 1) & 1, (t + 1) * 32);   // prefetch next A tile
        bf16x8 af[4], bfr[4];
        // B-fragments straight from global (L2-hot), no barrier dependence
#pragma unroll
        for (int n = 0; n < 4; ++n) bfr[n] = *(const bf16x8*)(bp[n] + t * 32);
#pragma unroll
        for (int m = 0; m < 4; ++m) af[m] = *(const bf16x8*)(&As[cur][offA[m]]);
#pragma unroll
        for (int m = 0; m < 4; ++m)
#pragma unroll
            for (int n = 0; n < 4; ++n)
                acc[m][n] = __builtin_amdgcn_mfma_f32_16x16x32_bf16(af[m], bfr[n], acc[m][n], 0, 0, 0);
        __syncthreads();   // drains only the A prefetch (half the prior bytes)
    }
    // C/D layout: col = lane&15, row = (lane>>4)*4 + j  [verified m89/m91]
    const int r0 = bm * 128 + wm * 64 + kg * 4;
    const int c0 = bn * 128 + wn * 64 + fr;
#pragma unroll
    for (int m = 0; m < 4; ++m)
#pragma unroll
        for (int n = 0; n < 4; ++n)
#pragma unroll
            for (int j = 0; j < 4; ++j) {
                size_t off = (size_t)(r0 + m * 16 + j) * N + (c0 + n * 16);
                if (OUT_BF16) ((__hip_bfloat16*)Cout)[off] = __float2bfloat16(acc[m][n][j]);
                else          ((float*)Cout)[off] = acc[m][n][j];
            }
}

// ---------------- fused softmax+collapse+fold (R12 verbatim, 47.0us) ----------------
// 8 px/block, 384 thr, image-per-XCD mapping. Phase A: 96 threads, one
// (pixel,head) each, 9-center softmax -> w25 in LDS (non-atomic). Phase B:
// 48 thr/pixel, 8 ch/thread, branchy 25-tap gather with 16B loads.
__global__ __launch_bounds__(384) void attn_fold(const __hip_bfloat16* __restrict__ va,
                                                 __hip_bfloat16* __restrict__ yb) {
    __shared__ float wls[8][300];
    const int tid = threadIdx.x;
    const int bid = blockIdx.x;
    const int b = bid & 7;            // image index == XCD index
    const int bi = bid >> 3;          // 0..391, spatial order within image
    const int rs0 = bi * 8;           // within-image pixel offset (392*8 = 3136)
    const u16* vap = (const u16*)va;

    if (tid < 96) {
        const int pixL = tid / 12, h = tid - pixL * 12;
        const int rs = rs0 + pixL;
        const int r = rs / 56, s = rs - r * 56;
        float w[25];
#pragma unroll
        for (int t = 0; t < 25; ++t) w[t] = 0.f;
        const float SC = 0.17677669529663687f;  // 1/sqrt(32)
#pragma unroll
        for (int i = 0; i < 3; ++i) {
            int cy = r + 1 - i;
            if ((unsigned)cy >= (unsigned)H_) continue;
#pragma unroll
            for (int j = 0; j < 3; ++j) {
                int cx = s + 1 - j;
                if ((unsigned)cx >= (unsigned)W_) continue;
                const u16* ap = vap + (size_t)(b * 3136 + cy * 56 + cx) * NPAD + C_ + h * 81 + (i * 3 + j) * 9;
                float aq[9];
                float mx = -1e30f;
#pragma unroll
                for (int qq = 0; qq < 9; ++qq) { aq[qq] = bf2f(ap[qq]); mx = fmaxf(mx, aq[qq]); }
                float ssum = 0.f;
#pragma unroll
                for (int qq = 0; qq < 9; ++qq) { aq[qq] = __expf((aq[qq] - mx) * SC); ssum += aq[qq]; }
                float inv = 1.f / ssum;
#pragma unroll
                for (int qi = 0; qi < 3; ++qi)
#pragma unroll
                    for (int qj = 0; qj < 3; ++qj)
                        w[(qi - i + 2) * 5 + (qj - j + 2)] += aq[qi * 3 + qj] * inv;
            }
        }
#pragma unroll
        for (int t = 0; t < 25; ++t) wls[pixL][t * 12 + h] = w[t];
    }
    __syncthreads();

    {
        const int g = tid / 48, t = tid - g * 48;
        const int c0 = t * 8, hh = t >> 2;
        const int rs = rs0 + g;
        const int r = rs / 56, s = rs - r * 56;
        float acc[8];
#pragma unroll
        for (int e = 0; e < 8; ++e) acc[e] = 0.f;
        const float* wp = &wls[g][hh];
#pragma unroll
        for (int dy = -2; dy <= 2; ++dy) {
            int py = r + dy;
            if ((unsigned)py >= (unsigned)H_) continue;
#pragma unroll
            for (int dx = -2; dx <= 2; ++dx) {
                int px = s + dx;
                if ((unsigned)px >= (unsigned)W_) continue;
                float w = wp[((dy + 2) * 5 + (dx + 2)) * 12];
                u16x8 v = *(const u16x8*)(vap + (size_t)(b * 3136 + py * 56 + px) * NPAD + c0);
#pragma unroll
                for (int e = 0; e < 8; ++e) acc[e] += w * bf2f(v[e]);
            }
        }
        u16x8 o;
#pragma unroll
        for (int e = 0; e < 8; ++e) o[e] = f2bf(acc[e]);
        *(u16x8*)((u16*)yb + (size_t)(b * 3136 + rs) * C_ + c0) = o;
    }
}

// ---------------- launch ----------------
extern "C" void kernel_launch(void* const* d_in, const int* in_sizes, int n_in,
                              void* d_out, int out_size, void* d_ws, size_t ws_size,
                              hipStream_t stream) {
    const float* x  = (const float*)d_in[0];
    const float* Wv = (const float*)d_in[1];
    const float* Wa = (const float*)d_in[2];
    const float* Wo = (const float*)d_in[3];
    char* ws = (char*)d_ws;
    // ws layout (bytes): xb@0 (19267584) | wcat@19267584 (1081344) |
    // wob@20348928 (294912) | va@20643840 (70647808) | yb@91291648 (19267584)
    u16*            xb   = (u16*)(ws);
    __hip_bfloat16* wcat = (__hip_bfloat16*)(ws + 19267584);
    __hip_bfloat16* wob  = (__hip_bfloat16*)(ws + 20348928);
    __hip_bfloat16* va   = (__hip_bfloat16*)(ws + 20643840);
    __hip_bfloat16* yb   = (__hip_bfloat16*)(ws + 91291648);

    hipLaunchKernelGGL(pack_kernel, dim3(2048), dim3(256), 0, stream,
                       x, Wv, Wa, Wo, xb, wcat, wob);

    // gemm1: 196 (M) x 11 (N) = 2156 blocks, XCD-chunked
    {
        int gridN = NPAD / 128, nwg = (NPIX / 128) * gridN;
        int q = nwg / 8, r = nwg % 8;
        hipLaunchKernelGGL(HIP_KERNEL_NAME(gemm_bt<1>), dim3(nwg), dim3(256), 0, stream,
                           (const u16*)xb, (const u16*)wcat, (void*)va, NPAD, KDIM, gridN, q, r);
    }
    hipLaunchKernelGGL(attn_fold, dim3(NPIX / 8), dim3(384), 0, stream, va, yb);
    // gemm2: 196 x 3 = 588 blocks, XCD-chunked
    {
        int gridN = C_ / 128, nwg = (NPIX / 128) * gridN;
        int q = nwg / 8, r = nwg % 8;
        hipLaunchKernelGGL(HIP_KERNEL_NAME(gemm_bt<0>), dim3(nwg), dim3(256), 0, stream,
                           (const u16*)yb, (const u16*)wob, d_out, C_, KDIM, gridN, q, r);
    }
}

// Round 18
// 117.912 us; speedup vs baseline: 1.2741x; 1.2741x over previous
//
#include <hip/hip_runtime.h>
#include <hip/hip_bf16.h>

#define B_ 8
#define H_ 56
#define W_ 56
#define C_ 384
#define HEADS_ 12
#define NPIX (B_*H_*W_)      // 25088
#define NPAD 1408            // 1356 padded to 11*128
#define KDIM 384

typedef unsigned short u16;
typedef __attribute__((ext_vector_type(4))) float f32x4;
typedef __attribute__((ext_vector_type(8))) short bf16x8;
typedef __attribute__((ext_vector_type(8))) unsigned short u16x8;

#define GLDS16(g, l)                                                            \
    __builtin_amdgcn_global_load_lds(                                           \
        (const __attribute__((address_space(1))) void*)(g),                     \
        (__attribute__((address_space(3))) void*)(l), 16, 0, 0)

__device__ __forceinline__ float bf2f(u16 u) {
    union { unsigned int uu; float f; } cv; cv.uu = ((unsigned)u) << 16; return cv.f;
}
__device__ __forceinline__ u16 f2bf(float f) {
    __hip_bfloat16 hb = __float2bfloat16(f);
    return *reinterpret_cast<u16*>(&hb);
}

// packed-pair LDS offset (u16 units) within one 128x32 tile (8KB), R4-verified
// zero-conflict: two 32-k rows share a 128B line; 8x16B slots XOR'd by line idx.
__device__ __forceinline__ int foff(int row, int kg) {
    int lrow = row >> 1;
    int s = (((row & 1) << 2) | kg) ^ (lrow & 7);
    return (lrow << 6) + (s << 3);
}

// ---------------- pack: fp32 -> bf16 (x vectorized, [Wv;Wa;0], Wo) ----------------
__global__ void pack_kernel(const float* __restrict__ x, const float* __restrict__ Wv,
                            const float* __restrict__ Wa, const float* __restrict__ Wo,
                            u16* __restrict__ xb, __hip_bfloat16* __restrict__ wcat,
                            __hip_bfloat16* __restrict__ wob) {
    const int NX8 = NPIX * C_ / 8;   // 1204224 (x in 8-float chunks)
    const int NW = NPAD * KDIM;      // 540672
    const int NO = C_ * C_;          // 147456
    const int total = NX8 + NW + NO;
    for (int idx = blockIdx.x * blockDim.x + threadIdx.x; idx < total;
         idx += gridDim.x * blockDim.x) {
        if (idx < NX8) {
            float4 a = ((const float4*)x)[idx * 2];
            float4 b = ((const float4*)x)[idx * 2 + 1];
            u16x8 o;
            o[0] = f2bf(a.x); o[1] = f2bf(a.y); o[2] = f2bf(a.z); o[3] = f2bf(a.w);
            o[4] = f2bf(b.x); o[5] = f2bf(b.y); o[6] = f2bf(b.z); o[7] = f2bf(b.w);
            ((u16x8*)xb)[idx] = o;
        } else if (idx < NX8 + NW) {
            int t = idx - NX8;
            int o = t / KDIM;
            float v = 0.f;
            if (o < 384) v = Wv[t];
            else if (o < 1356) v = Wa[t - 147456];
            wcat[t] = __float2bfloat16(v);
        } else {
            int t = idx - NX8 - NW;
            wob[t] = __float2bfloat16(Wo[t]);
        }
    }
}

// ---------------- bf16 MFMA GEMM: C[M,N] = A[M,K] * B[N,K]^T ----------------
// Final config (R9/R15, 118us end-to-end, reproduced twice): 128x128 tile,
// BK=32 DOUBLE-buffered (32KB LDS -> 5 blocks/CU), packed-pair zero-conflict
// LDS geometry, STAGE(t+1)-before-compute(t) prefetch, one drain/tile,
// T1 bijective XCD chunk swizzle.
// [Rejected by measurement: BK=64 dbuf 64KB (R8, occupancy cliff), 256-tile
//  (R14, VGPR+LDS cliff), B-direct-from-global (R16, vmcnt coupling),
//  4-ring counted-vmcnt 8-phase (R3/R4, too few K-steps at K=384).]
#define STAGE(buf_, kt_) do {                                                        \
    _Pragma("unroll") for (int j = 0; j < 2; ++j) {                                  \
        int chunk = wid * 128 + j * 64 + lane;      /* 0..511 16B chunks */          \
        int lrow = chunk >> 3, sl = chunk & 7;                                       \
        int u = sl ^ (lrow & 7);                                                     \
        int grow = lrow * 2 + (u >> 2);                                              \
        int gcol = (u & 3) << 3;                                                     \
        GLDS16(&A[(size_t)(bm * 128 + grow) * K + (kt_) + gcol],                     \
               &As[buf_][(wid * 128 + j * 64) * 8]);                                 \
        GLDS16(&Bw[(size_t)(bn * 128 + grow) * K + (kt_) + gcol],                    \
               &Bs[buf_][(wid * 128 + j * 64) * 8]);                                 \
    } } while (0)

template<int OUT_BF16>
__global__ __launch_bounds__(256) void gemm_bt(const u16* __restrict__ A, const u16* __restrict__ Bw,
                                               void* __restrict__ Cout, int N, int K,
                                               int gridN, int q, int r) {
    __shared__ u16 As[2][128 * 32];
    __shared__ u16 Bs[2][128 * 32];
    const int bid = blockIdx.x;
    const int xcd = bid & 7, ii = bid >> 3;
    const int logical = (xcd < r) ? xcd * (q + 1) + ii : r * (q + 1) + (xcd - r) * q + ii;
    const int bm = logical / gridN, bn = logical - bm * gridN;
    const int tid = threadIdx.x;
    const int lane = tid & 63, wid = tid >> 6;
    const int wm = wid >> 1, wn = wid & 1;
    const int fr = lane & 15;    // fragment row/col within 16
    const int kg = lane >> 4;    // k-group 0..3 (8 contiguous k each)
    const int NT = K >> 5;       // 12 for K=384
    f32x4 acc[4][4] = {};

    int offA[4], offB[4];
#pragma unroll
    for (int m = 0; m < 4; ++m) {
        offA[m] = foff(wm * 64 + m * 16 + fr, kg);
        offB[m] = foff(wn * 64 + m * 16 + fr, kg);
    }

    STAGE(0, 0);
    __syncthreads();
    for (int t = 0; t < NT; ++t) {
        const int cur = t & 1;
        if (t + 1 < NT) STAGE((t + 1) & 1, (t + 1) * 32);   // prefetch next tile
        bf16x8 af[4], bfr[4];
#pragma unroll
        for (int m = 0; m < 4; ++m) af[m] = *(const bf16x8*)(&As[cur][offA[m]]);
#pragma unroll
        for (int n = 0; n < 4; ++n) bfr[n] = *(const bf16x8*)(&Bs[cur][offB[n]]);
#pragma unroll
        for (int m = 0; m < 4; ++m)
#pragma unroll
            for (int n = 0; n < 4; ++n)
                acc[m][n] = __builtin_amdgcn_mfma_f32_16x16x32_bf16(af[m], bfr[n], acc[m][n], 0, 0, 0);
        __syncthreads();
    }
    // C/D layout: col = lane&15, row = (lane>>4)*4 + j  [verified m89/m91]
    const int r0 = bm * 128 + wm * 64 + kg * 4;
    const int c0 = bn * 128 + wn * 64 + fr;
#pragma unroll
    for (int m = 0; m < 4; ++m)
#pragma unroll
        for (int n = 0; n < 4; ++n)
#pragma unroll
            for (int j = 0; j < 4; ++j) {
                size_t off = (size_t)(r0 + m * 16 + j) * N + (c0 + n * 16);
                if (OUT_BF16) ((__hip_bfloat16*)Cout)[off] = __float2bfloat16(acc[m][n][j]);
                else          ((float*)Cout)[off] = acc[m][n][j];
            }
}

// ---------------- fused softmax+collapse+fold (47.0us measured) ----------------
// 8 px/block, 384 thr, image-per-XCD mapping. Phase A: 96 threads, one
// (pixel,head) each, 9-center softmax -> w25 in LDS (non-atomic). Phase B:
// 48 thr/pixel, 8 ch/thread, branchy 25-tap gather with 16B loads.
// [Rejected by measurement: branchless gather (R10, VGPR/occupancy), LDS
//  atomicAdd balance (R11, CAS+spill), 3-way i-split (R13, merge cost).]
__global__ __launch_bounds__(384) void attn_fold(const __hip_bfloat16* __restrict__ va,
                                                 __hip_bfloat16* __restrict__ yb) {
    __shared__ float wls[8][300];
    const int tid = threadIdx.x;
    const int bid = blockIdx.x;
    const int b = bid & 7;            // image index == XCD index
    const int bi = bid >> 3;          // 0..391, spatial order within image
    const int rs0 = bi * 8;           // within-image pixel offset (392*8 = 3136)
    const u16* vap = (const u16*)va;

    if (tid < 96) {
        const int pixL = tid / 12, h = tid - pixL * 12;
        const int rs = rs0 + pixL;
        const int r = rs / 56, s = rs - r * 56;
        float w[25];
#pragma unroll
        for (int t = 0; t < 25; ++t) w[t] = 0.f;
        const float SC = 0.17677669529663687f;  // 1/sqrt(32)
#pragma unroll
        for (int i = 0; i < 3; ++i) {
            int cy = r + 1 - i;
            if ((unsigned)cy >= (unsigned)H_) continue;
#pragma unroll
            for (int j = 0; j < 3; ++j) {
                int cx = s + 1 - j;
                if ((unsigned)cx >= (unsigned)W_) continue;
                const u16* ap = vap + (size_t)(b * 3136 + cy * 56 + cx) * NPAD + C_ + h * 81 + (i * 3 + j) * 9;
                float aq[9];
                float mx = -1e30f;
#pragma unroll
                for (int qq = 0; qq < 9; ++qq) { aq[qq] = bf2f(ap[qq]); mx = fmaxf(mx, aq[qq]); }
                float ssum = 0.f;
#pragma unroll
                for (int qq = 0; qq < 9; ++qq) { aq[qq] = __expf((aq[qq] - mx) * SC); ssum += aq[qq]; }
                float inv = 1.f / ssum;
#pragma unroll
                for (int qi = 0; qi < 3; ++qi)
#pragma unroll
                    for (int qj = 0; qj < 3; ++qj)
                        w[(qi - i + 2) * 5 + (qj - j + 2)] += aq[qi * 3 + qj] * inv;
            }
        }
#pragma unroll
        for (int t = 0; t < 25; ++t) wls[pixL][t * 12 + h] = w[t];
    }
    __syncthreads();

    {
        const int g = tid / 48, t = tid - g * 48;
        const int c0 = t * 8, hh = t >> 2;
        const int rs = rs0 + g;
        const int r = rs / 56, s = rs - r * 56;
        float acc[8];
#pragma unroll
        for (int e = 0; e < 8; ++e) acc[e] = 0.f;
        const float* wp = &wls[g][hh];
#pragma unroll
        for (int dy = -2; dy <= 2; ++dy) {
            int py = r + dy;
            if ((unsigned)py >= (unsigned)H_) continue;
#pragma unroll
            for (int dx = -2; dx <= 2; ++dx) {
                int px = s + dx;
                if ((unsigned)px >= (unsigned)W_) continue;
                float w = wp[((dy + 2) * 5 + (dx + 2)) * 12];
                u16x8 v = *(const u16x8*)(vap + (size_t)(b * 3136 + py * 56 + px) * NPAD + c0);
#pragma unroll
                for (int e = 0; e < 8; ++e) acc[e] += w * bf2f(v[e]);
            }
        }
        u16x8 o;
#pragma unroll
        for (int e = 0; e < 8; ++e) o[e] = f2bf(acc[e]);
        *(u16x8*)((u16*)yb + (size_t)(b * 3136 + rs) * C_ + c0) = o;
    }
}

// ---------------- launch ----------------
extern "C" void kernel_launch(void* const* d_in, const int* in_sizes, int n_in,
                              void* d_out, int out_size, void* d_ws, size_t ws_size,
                              hipStream_t stream) {
    const float* x  = (const float*)d_in[0];
    const float* Wv = (const float*)d_in[1];
    const float* Wa = (const float*)d_in[2];
    const float* Wo = (const float*)d_in[3];
    char* ws = (char*)d_ws;
    // ws layout (bytes): xb@0 (19267584) | wcat@19267584 (1081344) |
    // wob@20348928 (294912) | va@20643840 (70647808) | yb@91291648 (19267584)
    u16*            xb   = (u16*)(ws);
    __hip_bfloat16* wcat = (__hip_bfloat16*)(ws + 19267584);
    __hip_bfloat16* wob  = (__hip_bfloat16*)(ws + 20348928);
    __hip_bfloat16* va   = (__hip_bfloat16*)(ws + 20643840);
    __hip_bfloat16* yb   = (__hip_bfloat16*)(ws + 91291648);

    hipLaunchKernelGGL(pack_kernel, dim3(2048), dim3(256), 0, stream,
                       x, Wv, Wa, Wo, xb, wcat, wob);

    // gemm1: 196 (M) x 11 (N) = 2156 blocks, XCD-chunked
    {
        int gridN = NPAD / 128, nwg = (NPIX / 128) * gridN;
        int q = nwg / 8, r = nwg % 8;
        hipLaunchKernelGGL(HIP_KERNEL_NAME(gemm_bt<1>), dim3(nwg), dim3(256), 0, stream,
                           (const u16*)xb, (const u16*)wcat, (void*)va, NPAD, KDIM, gridN, q, r);
    }
    hipLaunchKernelGGL(attn_fold, dim3(NPIX / 8), dim3(384), 0, stream, va, yb);
    // gemm2: 196 x 3 = 588 blocks, XCD-chunked
    {
        int gridN = C_ / 128, nwg = (NPIX / 128) * gridN;
        int q = nwg / 8, r = nwg % 8;
        hipLaunchKernelGGL(HIP_KERNEL_NAME(gemm_bt<0>), dim3(nwg), dim3(256), 0, stream,
                           (const u16*)yb, (const u16*)wob, d_out, C_, KDIM, gridN, q, r);
    }
}